// Round 9
// baseline (133.382 us; speedup 1.0000x reference)
//
#include <hip/hip_runtime.h>
#include <hip/hip_bf16.h>
#include <math.h>

// Problem constants (B=512, D=768, H=256)
#define B 512
#define D 768
#define H 256
#define NN 128          // n = B/4
#define MM 256          // m = B/2
#define P_PAIRS 57280   // sum_{i=0}^{127} (511 - i)
#define NPBLK_P 448     // pair-tiles of 128 (last one half-padded)

typedef _Float16 f16x8 __attribute__((ext_vector_type(8)));
typedef float f32x4 __attribute__((ext_vector_type(4)));

// MFMA 16x16x32 f16:
//   A[m = lane&15][k = (lane>>4)*8 + e]; B from row-major [n][k] same pattern
//   C/D: col = lane&15, row = (lane>>4)*4 + reg
// W2 frag-tile: flat = ((g*8 + s)*64 + lane)*8 + e  <=>  W2[16g + (lane&15)][32s + (lane>>4)*8 + e]

// ---------------- K0: inv-norms [512] + W2 frag-tiles + zero ticket ----------------
__global__ __launch_bounds__(256) void k_norm(const float* __restrict__ emb,
                                              const float* __restrict__ W2,
                                              float* __restrict__ inv,
                                              _Float16* __restrict__ W2H,
                                              int* __restrict__ counter) {
    int bx = blockIdx.x;
    int t = threadIdx.x;
    if (bx < 32) {
        // rows 16bx..16bx+15; 16 threads per row, 48 els per thread
        __shared__ float ssq[16][17];
        int row16 = t >> 4, seg = t & 15;
        const float4* rp = (const float4*)(emb + (16 * bx + row16) * D + seg * 48);
        float ss = 0.f;
        #pragma unroll
        for (int it = 0; it < 12; it++) {
            float4 v = rp[it];
            ss += v.x * v.x + v.y * v.y + v.z * v.z + v.w * v.w;
        }
        ssq[row16][seg] = ss;
        __syncthreads();
        if (t < 16) {
            float s = 0.f;
            #pragma unroll
            for (int k = 0; k < 16; k++) s += ssq[t][k];
            inv[16 * bx + t] = 1.0f / fmaxf(sqrtf(s), 1e-12f);
        }
    } else {
        // W2H group g (16 groups, S=8)
        int g = bx - 32;
        if (g == 0 && t == 0) *counter = 0;
        #pragma unroll
        for (int it = 0; it < 2; it++) {
            int chunk = it * 256 + t;            // 0..511
            int s = chunk >> 6, lc = chunk & 63;
            int qq = lc >> 4, rr = lc & 15;
            const float* src = W2 + (16 * g + rr) * H + 32 * s + 8 * qq;
            float4 a = *(const float4*)src;
            float4 b = *(const float4*)(src + 4);
            f16x8 o;
            o[0] = (_Float16)a.x; o[1] = (_Float16)a.y; o[2] = (_Float16)a.z; o[3] = (_Float16)a.w;
            o[4] = (_Float16)b.x; o[5] = (_Float16)b.y; o[6] = (_Float16)b.z; o[7] = (_Float16)b.w;
            *(f16x8*)(W2H + ((g * 8 + s) * 64 + lc) * 8) = o;
        }
    }
}

// ---------------- K1: uv (128 blocks) + sim (16 blocks); direct emb/W1 reads ----------------
__global__ __launch_bounds__(256) void k_uvsim(const float* __restrict__ emb,
                                               const float* __restrict__ W1,
                                               const float* __restrict__ b1,
                                               const float* __restrict__ inv,
                                               _Float16* __restrict__ Up,
                                               _Float16* __restrict__ Vv,
                                               float* __restrict__ esp,   // [8][128]
                                               float* __restrict__ slp) { // [8][128]
    int bx = blockIdx.x;
    int w = threadIdx.x >> 6;
    int lane = threadIdx.x & 63;
    int r = lane & 15, q = lane >> 4;

    if (bx < 128) {
        // ---- uv tile: gm = bx>>2, gnp = (bx&3)*4 + w ----
        int gm = bx >> 2;
        int gnp = (bx & 3) * 4 + w;
        float invA = inv[16 * gm + r];
        const float* ap = emb + (16 * gm + r) * D + 8 * q;
        const float* wp[2];
        #pragma unroll
        for (int nt = 0; nt < 2; nt++) {
            int n = gnp * 32 + nt * 16 + r;      // 0..511
            wp[nt] = W1 + (n & 255) * (2 * D) + (n >> 8) * D + 8 * q;
        }
        f32x4 acc[2] = {};
        #pragma unroll 2
        for (int s = 0; s < 24; s++) {
            float4 a0 = *(const float4*)(ap + 32 * s);
            float4 a1 = *(const float4*)(ap + 32 * s + 4);
            f16x8 af;
            af[0] = (_Float16)(a0.x * invA); af[1] = (_Float16)(a0.y * invA);
            af[2] = (_Float16)(a0.z * invA); af[3] = (_Float16)(a0.w * invA);
            af[4] = (_Float16)(a1.x * invA); af[5] = (_Float16)(a1.y * invA);
            af[6] = (_Float16)(a1.z * invA); af[7] = (_Float16)(a1.w * invA);
            #pragma unroll
            for (int nt = 0; nt < 2; nt++) {
                float4 b0 = *(const float4*)(wp[nt] + 32 * s);
                float4 b1v = *(const float4*)(wp[nt] + 32 * s + 4);
                f16x8 bf;
                bf[0] = (_Float16)b0.x; bf[1] = (_Float16)b0.y;
                bf[2] = (_Float16)b0.z; bf[3] = (_Float16)b0.w;
                bf[4] = (_Float16)b1v.x; bf[5] = (_Float16)b1v.y;
                bf[6] = (_Float16)b1v.z; bf[7] = (_Float16)b1v.w;
                acc[nt] = __builtin_amdgcn_mfma_f32_16x16x32_f16(af, bf, acc[nt], 0, 0, 0);
            }
        }
        #pragma unroll
        for (int nt = 0; nt < 2; nt++) {
            int n = (gnp * 2 + nt) * 16 + r;
            float bias = (n < H) ? b1[n] : 0.f;
            #pragma unroll
            for (int rr = 0; rr < 4; rr++) {
                int m = gm * 16 + 4 * q + rr;
                float C = acc[nt][rr] + bias;
                if (n < H) Up[m * H + n] = (_Float16)C;
                else       Vv[m * H + (n - H)] = (_Float16)C;
            }
        }
    } else {
        // ---- sim tile: sb = bx-128 (0..15); gm = sb>>1; slot = (sb&1)*4 + w ----
        int sb = bx - 128;
        int gm = sb >> 1;                        // 0..7 (rows < 128)
        int slot = (sb & 1) * 4 + w;             // 0..7
        int gn0 = slot * 4;
        float invA = inv[16 * gm + r];
        float invB[4];
        const float* bp[4];
        #pragma unroll
        for (int nt = 0; nt < 4; nt++) {
            int n = (gn0 + nt) * 16 + r;
            invB[nt] = inv[n];
            bp[nt] = emb + n * D + 8 * q;
        }
        const float* ap = emb + (16 * gm + r) * D + 8 * q;
        f32x4 acc[4] = {};
        #pragma unroll 2
        for (int s = 0; s < 24; s++) {
            float4 a0 = *(const float4*)(ap + 32 * s);
            float4 a1 = *(const float4*)(ap + 32 * s + 4);
            f16x8 af;
            af[0] = (_Float16)(a0.x * invA); af[1] = (_Float16)(a0.y * invA);
            af[2] = (_Float16)(a0.z * invA); af[3] = (_Float16)(a0.w * invA);
            af[4] = (_Float16)(a1.x * invA); af[5] = (_Float16)(a1.y * invA);
            af[6] = (_Float16)(a1.z * invA); af[7] = (_Float16)(a1.w * invA);
            #pragma unroll
            for (int nt = 0; nt < 4; nt++) {
                float4 b0 = *(const float4*)(bp[nt] + 32 * s);
                float4 b1v = *(const float4*)(bp[nt] + 32 * s + 4);
                float ib = invB[nt];
                f16x8 bf;
                bf[0] = (_Float16)(b0.x * ib); bf[1] = (_Float16)(b0.y * ib);
                bf[2] = (_Float16)(b0.z * ib); bf[3] = (_Float16)(b0.w * ib);
                bf[4] = (_Float16)(b1v.x * ib); bf[5] = (_Float16)(b1v.y * ib);
                bf[6] = (_Float16)(b1v.z * ib); bf[7] = (_Float16)(b1v.w * ib);
                acc[nt] = __builtin_amdgcn_mfma_f32_16x16x32_f16(af, bf, acc[nt], 0, 0, 0);
            }
        }
        #pragma unroll
        for (int rr = 0; rr < 4; rr++) {
            int irow = gm * 16 + q * 4 + rr;
            float es = 0.f, sl = 0.f;
            #pragma unroll
            for (int nt = 0; nt < 4; nt++) {
                int kcol = (gn0 + nt) * 16 + r;
                float C = acc[nt][rr];
                if (kcol != irow) es += expf(2.f * C);
                if (kcol > irow && kcol < NN) sl += 2.f * C;
            }
            #pragma unroll
            for (int m = 1; m <= 8; m <<= 1) {
                es += __shfl_xor(es, m);
                sl += __shfl_xor(sl, m);
            }
            if (r == 0) {
                esp[slot * NN + irow] = es;
                slp[slot * NN + irow] = sl;
            }
        }
    }
}

// ---------------- K2: pair MLP (448 x 128-pair tiles) + folded final combine ----------------
__global__ __launch_bounds__(256, 2) void k_pairs(const _Float16* __restrict__ Up,
                                                  const _Float16* __restrict__ Vv,
                                                  const _Float16* __restrict__ W2H,
                                                  const float* __restrict__ b2,
                                                  const float* __restrict__ W3,
                                                  const float* __restrict__ b3,
                                                  const float* __restrict__ esp,
                                                  const float* __restrict__ slp,
                                                  float* __restrict__ bcepart,
                                                  int* __restrict__ counter,
                                                  float* __restrict__ out) {
    __shared__ _Float16 h1[128][264];    // 66 KB
    __shared__ int jj_s[128];
    __shared__ float redbuf[4][128];     // also reused as final-combine scratch
    __shared__ float red2[2];
    __shared__ int islast_s;

    int tid = threadIdx.x;
    int w = tid >> 6, lane = tid & 63;
    int r = lane & 15, q = lane >> 4;
    int bx = blockIdx.x;

    int p0 = bx * 128;
    if (tid < 128) {
        int p = p0 + tid;
        if (p >= P_PAIRS) p = P_PAIRS - 1;       // pad rows duplicate last pair (masked later)
        float disc = 1046529.f - 8.f * (float)p; // 1023^2 - 8p, exact in fp32
        int i = (int)((1023.f - sqrtf(disc)) * 0.5f);
        if (i < 0) i = 0;
        if (i > NN - 1) i = NN - 1;
        while (i > 0 && i * (1023 - i) / 2 > p) i--;
        while ((i + 1) * (1022 - i) / 2 <= p) i++;
        int j = i + 1 + (p - i * (1023 - i) / 2);
        jj_s[tid] = (i << 16) | j;
    }
    __syncthreads();

    // stage h1 = relu(U'[i] + V[j]) f16
    #pragma unroll
    for (int uu = 0; uu < 2; uu++) {
        int u = uu * 256 + tid;                  // 0..511
        int row = u >> 2, cq = u & 3;
        int ij = jj_s[row];
        int i = ij >> 16, j = ij & 0xffff;
        const _Float16* up = Up + i * H + 64 * cq;
        const _Float16* vp = Vv + j * H + 64 * cq;
        #pragma unroll
        for (int c8 = 0; c8 < 8; c8++) {
            f16x8 u8 = *(const f16x8*)(up + 8 * c8);
            f16x8 v8 = *(const f16x8*)(vp + 8 * c8);
            f16x8 zero = {};
            f16x8 hv = __builtin_elementwise_max(u8 + v8, zero);
            *(f16x8*)&h1[row][64 * cq + 8 * c8] = hv;
        }
    }
    __syncthreads();

    // MFMA: C[128 pairs][64 cols per wave] = h1 @ W2^T
    f32x4 acc[8][4] = {};                        // [mt][nt]
    #pragma unroll
    for (int s = 0; s < 8; s++) {
        f16x8 bb[4];
        #pragma unroll
        for (int nt = 0; nt < 4; nt++)
            bb[nt] = *(const f16x8*)(W2H + (((4 * w + nt) * 8 + s) * 64 + lane) * 8);
        #pragma unroll
        for (int mt = 0; mt < 8; mt++) {
            f16x8 a = *(const f16x8*)&h1[16 * mt + r][32 * s + 8 * q];
            #pragma unroll
            for (int nt = 0; nt < 4; nt++)
                acc[mt][nt] = __builtin_amdgcn_mfma_f32_16x16x32_f16(a, bb[nt], acc[mt][nt], 0, 0, 0);
        }
    }

    // epilogue: h2 = relu(C + b2), partial logit = sum_n h2*W3
    float b2v[4], w3v[4];
    #pragma unroll
    for (int nt = 0; nt < 4; nt++) {
        int n = 64 * w + 16 * nt + r;
        b2v[nt] = b2[n];
        w3v[nt] = W3[n];
    }
    #pragma unroll
    for (int mt = 0; mt < 8; mt++) {
        float part[4] = {0.f, 0.f, 0.f, 0.f};
        #pragma unroll
        for (int nt = 0; nt < 4; nt++)
            #pragma unroll
            for (int rr = 0; rr < 4; rr++) {
                float h2 = fmaxf(acc[mt][nt][rr] + b2v[nt], 0.f);
                part[rr] += h2 * w3v[nt];
            }
        #pragma unroll
        for (int rr = 0; rr < 4; rr++) {
            float v = part[rr];
            #pragma unroll
            for (int m = 1; m <= 8; m <<= 1) v += __shfl_xor(v, m);
            if (r == 0) redbuf[w][16 * mt + 4 * q + rr] = v;
        }
    }
    __syncthreads();

    if (tid < 128) {
        int p = p0 + tid;
        int j = jj_s[tid] & 0xffff;
        float lsum = 0.f;
        if (p < P_PAIRS) {
            float logit = redbuf[0][tid] + redbuf[1][tid] +
                          redbuf[2][tid] + redbuf[3][tid] + b3[0];
            float label = (j < MM) ? 1.f : 0.f;
            lsum = fmaxf(logit, 0.f) - logit * label + log1pf(expf(-fabsf(logit)));
        }
        #pragma unroll
        for (int off = 32; off > 0; off >>= 1) lsum += __shfl_down(lsum, off);
        if ((tid & 63) == 0) red2[tid >> 6] = lsum;
    }
    __syncthreads();

    // ---- ticket: last block does final combine ----
    if (tid == 0) {
        bcepart[bx] = red2[0] + red2[1];
        __threadfence();                         // release: bcepart visible before ticket
        int old = atomicAdd(counter, 1);
        islast_s = (old == NPBLK_P - 1);
    }
    __syncthreads();
    if (islast_s) {
        __threadfence();                         // acquire: see all bcepart stores
        float* fred = &redbuf[0][0];             // 256-float scratch (safe to reuse)
        float s = 0.f;
        for (int p = tid; p < NPBLK_P; p += 256) s += bcepart[p];
        fred[tid] = s;
        __syncthreads();
        for (int st = 128; st > 0; st >>= 1) {
            if (tid < st) fred[tid] += fred[tid + st];
            __syncthreads();
        }
        float bce_total = fred[0];
        __syncthreads();

        float v = 0.f;
        if (tid < NN) {
            float es = 0.f, sl = 0.f;
            #pragma unroll
            for (int s8 = 0; s8 < 8; s8++) {
                es += esp[s8 * NN + tid];
                sl += slp[s8 * NN + tid];
            }
            v = (float)(NN - 1 - tid) * logf(es) - sl;
        }
        fred[tid] = v;
        __syncthreads();
        for (int st = 128; st > 0; st >>= 1) {
            if (tid < st) fred[tid] += fred[tid + st];
            __syncthreads();
        }
        if (tid == 0) {
            float closs = (-2.0f * (float)(NN - 1) / (float)NN) * fred[0];
            out[0] = closs + bce_total / (float)P_PAIRS;
        }
    }
}

extern "C" void kernel_launch(void* const* d_in, const int* in_sizes, int n_in,
                              void* d_out, int out_size, void* d_ws, size_t ws_size,
                              hipStream_t stream) {
    const float* emb = (const float*)d_in[0];
    const float* W1  = (const float*)d_in[1];
    const float* b1  = (const float*)d_in[2];
    const float* W2  = (const float*)d_in[3];
    const float* b2  = (const float*)d_in[4];
    const float* W3  = (const float*)d_in[5];
    const float* b3  = (const float*)d_in[6];
    float* out = (float*)d_out;

    float* ws = (float*)d_ws;
    float* esp     = ws;                         // 8*128
    float* slp     = ws + 1024;                  // 8*128
    float* bcepart = ws + 2048;                  // 448
    float* inv     = ws + 2560;                  // 512
    int*   counter = (int*)(ws + 3072);          // 1
    _Float16* W2H = (_Float16*)(ws + 3136);      // 256*256
    _Float16* Up  = W2H + H * H;                 // 512*256
    _Float16* Vv  = Up + B * H;                  // 512*256

    k_norm<<<48, 256, 0, stream>>>(emb, W2, inv, W2H, counter);
    k_uvsim<<<144, 256, 0, stream>>>(emb, W1, b1, inv, Up, Vv, esp, slp);
    k_pairs<<<NPBLK_P, 256, 0, stream>>>(Up, Vv, W2H, b2, W3, b3,
                                         esp, slp, bcepart, counter, out);
}

// Round 10
// 111.104 us; speedup vs baseline: 1.2005x; 1.2005x over previous
//
#include <hip/hip_runtime.h>
#include <hip/hip_bf16.h>
#include <math.h>

// Problem constants (B=512, D=768, H=256)
#define B 512
#define D 768
#define H 256
#define NN 128          // n = B/4
#define MM 256          // m = B/2
#define P_PAIRS 57280   // sum_{i=0}^{127} (511 - i)
#define NPBLK_P 448     // pair-tiles of 128 (last one half-padded)

typedef _Float16 f16x8 __attribute__((ext_vector_type(8)));
typedef float f32x4 __attribute__((ext_vector_type(4)));

// MFMA 16x16x32 f16:
//   A[m = lane&15][k = (lane>>4)*8 + e]; B from row-major [n][k] same pattern
//   C/D: col = lane&15, row = (lane>>4)*4 + reg
// Frag-tile layout: flat = ((g*S + s)*64 + lane)*8 + e  <=>  M[16g + (lane&15)][32s + (lane>>4)*8 + e]

// ---------------- K0: z norms + zH frag-tiles (32 blk); W1H frag-tiles (64 blk); counter ----------------
__global__ __launch_bounds__(256) void k_prep(const float* __restrict__ emb,
                                              const float* __restrict__ W1,
                                              _Float16* __restrict__ zH,
                                              _Float16* __restrict__ W1H,
                                              int* __restrict__ counter) {
    __shared__ float invs[16];
    int bx = blockIdx.x;
    int tid = threadIdx.x;
    int w = tid >> 6, lane = tid & 63;

    if (bx < 32) {
        // z group g: normalize rows 16g..16g+15, write frag-tiles
        int g = bx;
        for (int rr = 0; rr < 4; rr++) {
            int row = 16 * g + 4 * w + rr;
            const float* rp = emb + row * D;
            float ss = 0.f;
            #pragma unroll
            for (int it = 0; it < 12; it++) {
                float v = rp[lane + 64 * it];
                ss += v * v;
            }
            #pragma unroll
            for (int m = 1; m <= 32; m <<= 1) ss += __shfl_xor(ss, m);
            if (lane == 0) invs[4 * w + rr] = 1.0f / fmaxf(sqrtf(ss), 1e-12f);
        }
        __syncthreads();
        for (int it = 0; it < 6; it++) {
            int chunk = it * 256 + tid;          // 0..1535
            int s = chunk >> 6, lc = chunk & 63;
            int qq = lc >> 4, rr = lc & 15;
            const float* src = emb + (16 * g + rr) * D + 32 * s + 8 * qq;
            float inv = invs[rr];
            float4 a = *(const float4*)src;
            float4 bb = *(const float4*)(src + 4);
            f16x8 o;
            o[0] = (_Float16)(a.x * inv); o[1] = (_Float16)(a.y * inv);
            o[2] = (_Float16)(a.z * inv); o[3] = (_Float16)(a.w * inv);
            o[4] = (_Float16)(bb.x * inv); o[5] = (_Float16)(bb.y * inv);
            o[6] = (_Float16)(bb.z * inv); o[7] = (_Float16)(bb.w * inv);
            *(f16x8*)(zH + ((g * 24 + s) * 64 + lc) * 8) = o;
        }
    } else {
        // W1H: group g = (bx-32)>>1, s-half h = (bx-32)&1; row n=16g+r reads W1[n&255][(n>>8)*768+k]
        int g = (bx - 32) >> 1;
        int h = (bx - 32) & 1;
        if (bx == 32 && tid == 0) *counter = 0;
        for (int it = 0; it < 3; it++) {
            int chunk = it * 256 + tid;          // 0..767
            int s = h * 12 + (chunk >> 6);
            int lc = chunk & 63;
            int qq = lc >> 4, rr = lc & 15;
            int n = 16 * g + rr;
            const float* src = W1 + (n & 255) * (2 * D) + (n >> 8) * D + 32 * s + 8 * qq;
            float4 a = *(const float4*)src;
            float4 bb = *(const float4*)(src + 4);
            f16x8 o;
            o[0] = (_Float16)a.x; o[1] = (_Float16)a.y; o[2] = (_Float16)a.z; o[3] = (_Float16)a.w;
            o[4] = (_Float16)bb.x; o[5] = (_Float16)bb.y; o[6] = (_Float16)bb.z; o[7] = (_Float16)bb.w;
            *(f16x8*)(W1H + ((g * 24 + s) * 64 + lc) * 8) = o;
        }
    }
}

// ---------------- K1: uv (128 blk) + sim (16 blk) + W2H convert (16 blk) ----------------
__global__ __launch_bounds__(256) void k_uvsim(const _Float16* __restrict__ zH,
                                               const _Float16* __restrict__ W1H,
                                               const float* __restrict__ W2,
                                               const float* __restrict__ b1,
                                               _Float16* __restrict__ Up,
                                               _Float16* __restrict__ Vv,
                                               _Float16* __restrict__ W2H,
                                               float* __restrict__ esp,   // [8][128]
                                               float* __restrict__ slp) { // [8][128]
    int bx = blockIdx.x;
    int tid = threadIdx.x;
    int w = tid >> 6;
    int lane = tid & 63;
    int r = lane & 15, q = lane >> 4;

    if (bx < 128) {
        // ---- uv tile gid = bx*4+w: U' = z@W1a^T + b1 ; V = z@W1b^T (f16 out) ----
        int gid = bx * 4 + w;                    // 0..511
        int gm = gid >> 4;                       // 0..31
        int gnp = gid & 15;                      // n-tile pair
        f32x4 acc[2] = {};
        #pragma unroll 4
        for (int s = 0; s < 24; s++) {
            f16x8 a = *(const f16x8*)(zH + ((gm * 24 + s) * 64 + lane) * 8);
            #pragma unroll
            for (int nt = 0; nt < 2; nt++) {
                f16x8 bb = *(const f16x8*)(W1H + (((gnp * 2 + nt) * 24 + s) * 64 + lane) * 8);
                acc[nt] = __builtin_amdgcn_mfma_f32_16x16x32_f16(a, bb, acc[nt], 0, 0, 0);
            }
        }
        #pragma unroll
        for (int nt = 0; nt < 2; nt++) {
            int n = (gnp * 2 + nt) * 16 + r;
            float bias = (n < H) ? b1[n] : 0.f;
            #pragma unroll
            for (int rr = 0; rr < 4; rr++) {
                int m = gm * 16 + 4 * q + rr;
                float C = acc[nt][rr] + bias;
                if (n < H) Up[m * H + n] = (_Float16)C;
                else       Vv[m * H + (n - H)] = (_Float16)C;
            }
        }
    } else if (bx < 144) {
        // ---- sim tile t = (bx-128)*4+w ----
        int t = (bx - 128) * 4 + w;              // 0..63
        int gm = t >> 3;                         // rows < 128
        int slot = t & 7;
        int gn0 = slot * 4;
        f32x4 acc[4] = {};
        #pragma unroll 4
        for (int s = 0; s < 24; s++) {
            f16x8 a = *(const f16x8*)(zH + ((gm * 24 + s) * 64 + lane) * 8);
            #pragma unroll
            for (int nt = 0; nt < 4; nt++) {
                f16x8 bb = *(const f16x8*)(zH + (((gn0 + nt) * 24 + s) * 64 + lane) * 8);
                acc[nt] = __builtin_amdgcn_mfma_f32_16x16x32_f16(a, bb, acc[nt], 0, 0, 0);
            }
        }
        #pragma unroll
        for (int rr = 0; rr < 4; rr++) {
            int irow = gm * 16 + q * 4 + rr;
            float es = 0.f, sl = 0.f;
            #pragma unroll
            for (int nt = 0; nt < 4; nt++) {
                int kcol = (gn0 + nt) * 16 + r;
                float C = acc[nt][rr];
                if (kcol != irow) es += expf(2.f * C);
                if (kcol > irow && kcol < NN) sl += 2.f * C;
            }
            #pragma unroll
            for (int m = 1; m <= 8; m <<= 1) {
                es += __shfl_xor(es, m);
                sl += __shfl_xor(sl, m);
            }
            if (r == 0) {
                esp[slot * NN + irow] = es;
                slp[slot * NN + irow] = sl;
            }
        }
    } else {
        // ---- W2H frag-tiles: group g (16 groups, S=8) ----
        int g = bx - 144;
        #pragma unroll
        for (int it = 0; it < 2; it++) {
            int chunk = it * 256 + tid;          // 0..511
            int s = chunk >> 6, lc = chunk & 63;
            int qq = lc >> 4, rr = lc & 15;
            const float* src = W2 + (16 * g + rr) * H + 32 * s + 8 * qq;
            float4 a = *(const float4*)src;
            float4 bb = *(const float4*)(src + 4);
            f16x8 o;
            o[0] = (_Float16)a.x; o[1] = (_Float16)a.y; o[2] = (_Float16)a.z; o[3] = (_Float16)a.w;
            o[4] = (_Float16)bb.x; o[5] = (_Float16)bb.y; o[6] = (_Float16)bb.z; o[7] = (_Float16)bb.w;
            *(f16x8*)(W2H + ((g * 8 + s) * 64 + lc) * 8) = o;
        }
    }
}

// ---------------- K2: pair MLP (448 x 128-pair tiles) + folded final combine ----------------
__global__ __launch_bounds__(256, 2) void k_pairs(const _Float16* __restrict__ Up,
                                                  const _Float16* __restrict__ Vv,
                                                  const _Float16* __restrict__ W2H,
                                                  const float* __restrict__ b2,
                                                  const float* __restrict__ W3,
                                                  const float* __restrict__ b3,
                                                  const float* __restrict__ esp,
                                                  const float* __restrict__ slp,
                                                  float* __restrict__ bcepart,
                                                  int* __restrict__ counter,
                                                  float* __restrict__ out) {
    __shared__ _Float16 h1[128][264];    // 66 KB
    __shared__ int jj_s[128];
    __shared__ float redbuf[4][128];     // also reused as final-combine scratch
    __shared__ float red2[2];
    __shared__ int islast_s;

    int tid = threadIdx.x;
    int w = tid >> 6, lane = tid & 63;
    int r = lane & 15, q = lane >> 4;
    int bx = blockIdx.x;

    int p0 = bx * 128;
    if (tid < 128) {
        int p = p0 + tid;
        if (p >= P_PAIRS) p = P_PAIRS - 1;       // pad rows duplicate last pair (masked later)
        float disc = 1046529.f - 8.f * (float)p; // 1023^2 - 8p, exact in fp32
        int i = (int)((1023.f - sqrtf(disc)) * 0.5f);
        if (i < 0) i = 0;
        if (i > NN - 1) i = NN - 1;
        while (i > 0 && i * (1023 - i) / 2 > p) i--;
        while ((i + 1) * (1022 - i) / 2 <= p) i++;
        int j = i + 1 + (p - i * (1023 - i) / 2);
        jj_s[tid] = (i << 16) | j;
    }
    __syncthreads();

    // stage h1 = relu(U'[i] + V[j]) f16
    #pragma unroll
    for (int uu = 0; uu < 2; uu++) {
        int u = uu * 256 + tid;                  // 0..511
        int row = u >> 2, cq = u & 3;
        int ij = jj_s[row];
        int i = ij >> 16, j = ij & 0xffff;
        const _Float16* up = Up + i * H + 64 * cq;
        const _Float16* vp = Vv + j * H + 64 * cq;
        #pragma unroll
        for (int c8 = 0; c8 < 8; c8++) {
            f16x8 u8 = *(const f16x8*)(up + 8 * c8);
            f16x8 v8 = *(const f16x8*)(vp + 8 * c8);
            f16x8 zero = {};
            f16x8 hv = __builtin_elementwise_max(u8 + v8, zero);
            *(f16x8*)&h1[row][64 * cq + 8 * c8] = hv;
        }
    }
    __syncthreads();

    // MFMA: C[128 pairs][64 cols per wave] = h1 @ W2^T
    f32x4 acc[8][4] = {};                        // [mt][nt]
    #pragma unroll
    for (int s = 0; s < 8; s++) {
        f16x8 bb[4];
        #pragma unroll
        for (int nt = 0; nt < 4; nt++)
            bb[nt] = *(const f16x8*)(W2H + (((4 * w + nt) * 8 + s) * 64 + lane) * 8);
        #pragma unroll
        for (int mt = 0; mt < 8; mt++) {
            f16x8 a = *(const f16x8*)&h1[16 * mt + r][32 * s + 8 * q];
            #pragma unroll
            for (int nt = 0; nt < 4; nt++)
                acc[mt][nt] = __builtin_amdgcn_mfma_f32_16x16x32_f16(a, bb[nt], acc[mt][nt], 0, 0, 0);
        }
    }

    // epilogue: h2 = relu(C + b2), partial logit = sum_n h2*W3
    float b2v[4], w3v[4];
    #pragma unroll
    for (int nt = 0; nt < 4; nt++) {
        int n = 64 * w + 16 * nt + r;
        b2v[nt] = b2[n];
        w3v[nt] = W3[n];
    }
    #pragma unroll
    for (int mt = 0; mt < 8; mt++) {
        float part[4] = {0.f, 0.f, 0.f, 0.f};
        #pragma unroll
        for (int nt = 0; nt < 4; nt++)
            #pragma unroll
            for (int rr = 0; rr < 4; rr++) {
                float h2 = fmaxf(acc[mt][nt][rr] + b2v[nt], 0.f);
                part[rr] += h2 * w3v[nt];
            }
        #pragma unroll
        for (int rr = 0; rr < 4; rr++) {
            float v = part[rr];
            #pragma unroll
            for (int m = 1; m <= 8; m <<= 1) v += __shfl_xor(v, m);
            if (r == 0) redbuf[w][16 * mt + 4 * q + rr] = v;
        }
    }
    __syncthreads();

    if (tid < 128) {
        int p = p0 + tid;
        int j = jj_s[tid] & 0xffff;
        float lsum = 0.f;
        if (p < P_PAIRS) {
            float logit = redbuf[0][tid] + redbuf[1][tid] +
                          redbuf[2][tid] + redbuf[3][tid] + b3[0];
            float label = (j < MM) ? 1.f : 0.f;
            lsum = fmaxf(logit, 0.f) - logit * label + log1pf(expf(-fabsf(logit)));
        }
        #pragma unroll
        for (int off = 32; off > 0; off >>= 1) lsum += __shfl_down(lsum, off);
        if ((tid & 63) == 0) red2[tid >> 6] = lsum;
    }
    __syncthreads();

    // ---- ticket: last block does final combine ----
    if (tid == 0) {
        bcepart[bx] = red2[0] + red2[1];
        __threadfence();                         // release: bcepart visible before ticket
        int old = atomicAdd(counter, 1);
        islast_s = (old == NPBLK_P - 1);
    }
    __syncthreads();
    if (islast_s) {
        __threadfence();                         // acquire
        float* fred = &redbuf[0][0];             // 256-float scratch
        float s = 0.f;
        for (int p = tid; p < NPBLK_P; p += 256) s += bcepart[p];
        fred[tid] = s;
        __syncthreads();
        for (int st = 128; st > 0; st >>= 1) {
            if (tid < st) fred[tid] += fred[tid + st];
            __syncthreads();
        }
        float bce_total = fred[0];
        __syncthreads();

        float v = 0.f;
        if (tid < NN) {
            float es = 0.f, sl = 0.f;
            #pragma unroll
            for (int s8 = 0; s8 < 8; s8++) {
                es += esp[s8 * NN + tid];
                sl += slp[s8 * NN + tid];
            }
            v = (float)(NN - 1 - tid) * logf(es) - sl;
        }
        fred[tid] = v;
        __syncthreads();
        for (int st = 128; st > 0; st >>= 1) {
            if (tid < st) fred[tid] += fred[tid + st];
            __syncthreads();
        }
        if (tid == 0) {
            float closs = (-2.0f * (float)(NN - 1) / (float)NN) * fred[0];
            out[0] = closs + bce_total / (float)P_PAIRS;
        }
    }
}

extern "C" void kernel_launch(void* const* d_in, const int* in_sizes, int n_in,
                              void* d_out, int out_size, void* d_ws, size_t ws_size,
                              hipStream_t stream) {
    const float* emb = (const float*)d_in[0];
    const float* W1  = (const float*)d_in[1];
    const float* b1  = (const float*)d_in[2];
    const float* W2  = (const float*)d_in[3];
    const float* b2  = (const float*)d_in[4];
    const float* W3  = (const float*)d_in[5];
    const float* b3  = (const float*)d_in[6];
    float* out = (float*)d_out;

    float* ws = (float*)d_ws;
    float* esp     = ws;                         // 8*128
    float* slp     = ws + 1024;                  // 8*128
    float* bcepart = ws + 2048;                  // 448
    int*   counter = (int*)(ws + 2560);          // 1
    _Float16* zH  = (_Float16*)(ws + 3072);      // 512*768 frag-tiled
    _Float16* W1H = zH + B * D;                  // 512*768 frag-tiled
    _Float16* W2H = W1H + 2 * H * D;             // 256*256 frag-tiled
    _Float16* Up  = W2H + H * H;                 // 512*256 row-major
    _Float16* Vv  = Up + B * H;                  // 512*256 row-major

    k_prep<<<96, 256, 0, stream>>>(emb, W1, zH, W1H, counter);
    k_uvsim<<<160, 256, 0, stream>>>(zH, W1H, W2, b1, Up, Vv, W2H, esp, slp);
    k_pairs<<<NPBLK_P, 256, 0, stream>>>(Up, Vv, W2H, b2, W3, b3,
                                         esp, slp, bcepart, counter, out);
}

// Round 11
// 101.208 us; speedup vs baseline: 1.3179x; 1.0978x over previous
//
#include <hip/hip_runtime.h>
#include <hip/hip_bf16.h>
#include <math.h>

// Problem constants (B=512, D=768, H=256)
#define B 512
#define D 768
#define H 256
#define NN 128          // n = B/4
#define MM 256          // m = B/2
#define P_PAIRS 57280   // sum_{i=0}^{127} (511 - i)
#define NPBLK_P 448     // pair-tiles of 128 (last one half-padded)

typedef _Float16 f16x8 __attribute__((ext_vector_type(8)));
typedef float f32x4 __attribute__((ext_vector_type(4)));

// MFMA 16x16x32 f16:
//   A[m = lane&15][k = (lane>>4)*8 + e]; B from row-major [n][k] same pattern
//   C/D: col = lane&15, row = (lane>>4)*4 + reg
// Frag-tile layout: flat = ((g*S + s)*64 + lane)*8 + e  <=>  M[16g + (lane&15)][32s + (lane>>4)*8 + e]

// ---------------- K0: prep, 160 blocks ----------------
// blocks [0,64):    z rows [8bx, 8bx+8) -> norms + zH frag-tiles
// blocks [64,128):  W1H frag-tiles (group (bx-64)>>1, s-half (bx-64)&1)
// blocks [128,160): W2H frag-tiles (group (bx-128)>>1, s-half (bx-128)&1)
__global__ __launch_bounds__(256) void k_prep(const float* __restrict__ emb,
                                              const float* __restrict__ W1,
                                              const float* __restrict__ W2,
                                              _Float16* __restrict__ zH,
                                              _Float16* __restrict__ W1H,
                                              _Float16* __restrict__ W2H) {
    __shared__ float invs[8];
    int bx = blockIdx.x;
    int tid = threadIdx.x;
    int w = tid >> 6, lane = tid & 63;

    if (bx < 64) {
        int g8 = bx;                    // 8-row block
        int grp = g8 >> 1;              // frag group 0..31
        int h = g8 & 1;                 // row half within group
        // phase 1: norms (wave w -> rows 2w, 2w+1)
        #pragma unroll
        for (int rr = 0; rr < 2; rr++) {
            int r8 = 2 * w + rr;        // 0..7
            const float* rp = emb + (8 * g8 + r8) * D;
            float ss = 0.f;
            #pragma unroll
            for (int it = 0; it < 12; it++) {
                float v = rp[lane + 64 * it];
                ss += v * v;
            }
            #pragma unroll
            for (int m = 1; m <= 32; m <<= 1) ss += __shfl_xor(ss, m);
            if (lane == 0) invs[r8] = 1.0f / fmaxf(sqrtf(ss), 1e-12f);
        }
        __syncthreads();
        // phase 2: 768 chunks = 24 s x 4 q x 8 r8
        #pragma unroll
        for (int it = 0; it < 3; it++) {
            int chunk = it * 256 + tid;
            int s = chunk >> 5;
            int x = chunk & 31;
            int q = x >> 3, r8 = x & 7;
            int r = h * 8 + r8;
            const float* src = emb + (8 * g8 + r8) * D + 32 * s + 8 * q;
            float inv = invs[r8];
            float4 a = *(const float4*)src;
            float4 bb = *(const float4*)(src + 4);
            f16x8 o;
            o[0] = (_Float16)(a.x * inv); o[1] = (_Float16)(a.y * inv);
            o[2] = (_Float16)(a.z * inv); o[3] = (_Float16)(a.w * inv);
            o[4] = (_Float16)(bb.x * inv); o[5] = (_Float16)(bb.y * inv);
            o[6] = (_Float16)(bb.z * inv); o[7] = (_Float16)(bb.w * inv);
            *(f16x8*)(zH + ((grp * 24 + s) * 64 + q * 16 + r) * 8) = o;
        }
    } else if (bx < 128) {
        // W1H: row n = 16g+r reads W1[n&255][(n>>8)*768 + k]
        int g = (bx - 64) >> 1;
        int sh = (bx - 64) & 1;
        #pragma unroll
        for (int it = 0; it < 3; it++) {
            int chunk = it * 256 + tid;          // 0..767
            int s = sh * 12 + (chunk >> 6);
            int lc = chunk & 63;
            int q = lc >> 4, r = lc & 15;
            int n = 16 * g + r;
            const float* src = W1 + (n & 255) * (2 * D) + (n >> 8) * D + 32 * s + 8 * q;
            float4 a = *(const float4*)src;
            float4 bb = *(const float4*)(src + 4);
            f16x8 o;
            o[0] = (_Float16)a.x; o[1] = (_Float16)a.y; o[2] = (_Float16)a.z; o[3] = (_Float16)a.w;
            o[4] = (_Float16)bb.x; o[5] = (_Float16)bb.y; o[6] = (_Float16)bb.z; o[7] = (_Float16)bb.w;
            *(f16x8*)(W1H + ((g * 24 + s) * 64 + lc) * 8) = o;
        }
    } else {
        // W2H: group g, s-half sh; 256 chunks = 4 s x 64 lc
        int g = (bx - 128) >> 1;
        int sh = (bx - 128) & 1;
        int s = sh * 4 + (tid >> 6);
        int lc = tid & 63;
        int q = lc >> 4, r = lc & 15;
        const float* src = W2 + (16 * g + r) * H + 32 * s + 8 * q;
        float4 a = *(const float4*)src;
        float4 bb = *(const float4*)(src + 4);
        f16x8 o;
        o[0] = (_Float16)a.x; o[1] = (_Float16)a.y; o[2] = (_Float16)a.z; o[3] = (_Float16)a.w;
        o[4] = (_Float16)bb.x; o[5] = (_Float16)bb.y; o[6] = (_Float16)bb.z; o[7] = (_Float16)bb.w;
        *(f16x8*)(W2H + ((g * 8 + s) * 64 + lc) * 8) = o;
    }
}

// ---------------- K1: uv, 256 blocks x 128 threads (2 wave-tiles per block) ----------------
__global__ __launch_bounds__(128) void k_uv(const _Float16* __restrict__ zH,
                                            const _Float16* __restrict__ W1H,
                                            const float* __restrict__ b1,
                                            _Float16* __restrict__ Up,
                                            _Float16* __restrict__ Vv) {
    int w = threadIdx.x >> 6;
    int lane = threadIdx.x & 63;
    int r = lane & 15, q = lane >> 4;
    int gid = blockIdx.x * 2 + w;            // 0..511
    int gm = gid >> 4;                       // 0..31
    int gnp = gid & 15;                      // n-tile pair

    f32x4 acc[2] = {};
    #pragma unroll 4
    for (int s = 0; s < 24; s++) {
        f16x8 a = *(const f16x8*)(zH + ((gm * 24 + s) * 64 + lane) * 8);
        #pragma unroll
        for (int nt = 0; nt < 2; nt++) {
            f16x8 bb = *(const f16x8*)(W1H + (((gnp * 2 + nt) * 24 + s) * 64 + lane) * 8);
            acc[nt] = __builtin_amdgcn_mfma_f32_16x16x32_f16(a, bb, acc[nt], 0, 0, 0);
        }
    }
    #pragma unroll
    for (int nt = 0; nt < 2; nt++) {
        int n = (gnp * 2 + nt) * 16 + r;
        float bias = (n < H) ? b1[n] : 0.f;
        #pragma unroll
        for (int rr = 0; rr < 4; rr++) {
            int m = gm * 16 + 4 * q + rr;
            float C = acc[nt][rr] + bias;
            if (n < H) Up[m * H + n] = (_Float16)C;
            else       Vv[m * H + (n - H)] = (_Float16)C;
        }
    }
}

// ---------------- K2: pair MLP (448 x 128-pair tiles) + sim rides in blocks [448,464) ----------------
__global__ __launch_bounds__(256, 2) void k_pairs(const _Float16* __restrict__ Up,
                                                  const _Float16* __restrict__ Vv,
                                                  const _Float16* __restrict__ W2H,
                                                  const _Float16* __restrict__ zH,
                                                  const float* __restrict__ b2,
                                                  const float* __restrict__ W3,
                                                  const float* __restrict__ b3,
                                                  float* __restrict__ bcepart,
                                                  float* __restrict__ esp,   // [8][128]
                                                  float* __restrict__ slp) { // [8][128]
    int tid = threadIdx.x;
    int w = tid >> 6, lane = tid & 63;
    int r = lane & 15, q = lane >> 4;
    int bx = blockIdx.x;

    if (bx >= NPBLK_P) {
        // ---- similarity stats: wave tile t = (bx-448)*4+w ----
        int t = (bx - NPBLK_P) * 4 + w;      // 0..63
        int gm = t >> 3;                     // rows < 128
        int slot = t & 7;
        int gn0 = slot * 4;
        f32x4 acc[4] = {};
        #pragma unroll 4
        for (int s = 0; s < 24; s++) {
            f16x8 a = *(const f16x8*)(zH + ((gm * 24 + s) * 64 + lane) * 8);
            #pragma unroll
            for (int nt = 0; nt < 4; nt++) {
                f16x8 bb = *(const f16x8*)(zH + (((gn0 + nt) * 24 + s) * 64 + lane) * 8);
                acc[nt] = __builtin_amdgcn_mfma_f32_16x16x32_f16(a, bb, acc[nt], 0, 0, 0);
            }
        }
        #pragma unroll
        for (int rr = 0; rr < 4; rr++) {
            int irow = gm * 16 + q * 4 + rr;
            float es = 0.f, sl = 0.f;
            #pragma unroll
            for (int nt = 0; nt < 4; nt++) {
                int kcol = (gn0 + nt) * 16 + r;
                float C = acc[nt][rr];
                if (kcol != irow) es += expf(2.f * C);
                if (kcol > irow && kcol < NN) sl += 2.f * C;
            }
            #pragma unroll
            for (int m = 1; m <= 8; m <<= 1) {
                es += __shfl_xor(es, m);
                sl += __shfl_xor(sl, m);
            }
            if (r == 0) {
                esp[slot * NN + irow] = es;
                slp[slot * NN + irow] = sl;
            }
        }
        return;
    }

    // ---- pair blocks ----
    __shared__ _Float16 h1[128][264];    // 66 KB
    __shared__ float redbuf[4][128];
    __shared__ float red2[2];

    int p0 = bx * 128;

    // stage h1 = relu(U'[i] + V[j]) f16; (i,j) computed inline per unit (no barrier)
    #pragma unroll
    for (int uu = 0; uu < 2; uu++) {
        int u = uu * 256 + tid;              // 0..511
        int row = u >> 2, cq = u & 3;
        int p = p0 + row;
        if (p >= P_PAIRS) p = P_PAIRS - 1;   // pad rows duplicate last pair (masked later)
        float disc = 1046529.f - 8.f * (float)p;   // 1023^2 - 8p, exact in fp32
        int i = (int)((1023.f - sqrtf(disc)) * 0.5f);
        if (i < 0) i = 0;
        if (i > NN - 1) i = NN - 1;
        while (i > 0 && i * (1023 - i) / 2 > p) i--;
        while ((i + 1) * (1022 - i) / 2 <= p) i++;
        int j = i + 1 + (p - i * (1023 - i) / 2);

        const _Float16* up = Up + i * H + 64 * cq;
        const _Float16* vp = Vv + j * H + 64 * cq;
        #pragma unroll
        for (int c8 = 0; c8 < 8; c8++) {
            f16x8 u8 = *(const f16x8*)(up + 8 * c8);
            f16x8 v8 = *(const f16x8*)(vp + 8 * c8);
            f16x8 zero = {};
            f16x8 hv = __builtin_elementwise_max(u8 + v8, zero);
            *(f16x8*)&h1[row][64 * cq + 8 * c8] = hv;
        }
    }
    __syncthreads();

    // MFMA: C[128 pairs][64 cols per wave] = h1 @ W2^T
    f32x4 acc[8][4] = {};                    // [mt][nt]
    #pragma unroll
    for (int s = 0; s < 8; s++) {
        f16x8 bb[4];
        #pragma unroll
        for (int nt = 0; nt < 4; nt++)
            bb[nt] = *(const f16x8*)(W2H + (((4 * w + nt) * 8 + s) * 64 + lane) * 8);
        #pragma unroll
        for (int mt = 0; mt < 8; mt++) {
            f16x8 a = *(const f16x8*)&h1[16 * mt + r][32 * s + 8 * q];
            #pragma unroll
            for (int nt = 0; nt < 4; nt++)
                acc[mt][nt] = __builtin_amdgcn_mfma_f32_16x16x32_f16(a, bb[nt], acc[mt][nt], 0, 0, 0);
        }
    }

    // epilogue: h2 = relu(C + b2), partial logit = sum_n h2*W3
    float b2v[4], w3v[4];
    #pragma unroll
    for (int nt = 0; nt < 4; nt++) {
        int n = 64 * w + 16 * nt + r;
        b2v[nt] = b2[n];
        w3v[nt] = W3[n];
    }
    #pragma unroll
    for (int mt = 0; mt < 8; mt++) {
        float part[4] = {0.f, 0.f, 0.f, 0.f};
        #pragma unroll
        for (int nt = 0; nt < 4; nt++)
            #pragma unroll
            for (int rr = 0; rr < 4; rr++) {
                float h2 = fmaxf(acc[mt][nt][rr] + b2v[nt], 0.f);
                part[rr] += h2 * w3v[nt];
            }
        #pragma unroll
        for (int rr = 0; rr < 4; rr++) {
            float v = part[rr];
            #pragma unroll
            for (int m = 1; m <= 8; m <<= 1) v += __shfl_xor(v, m);
            if (r == 0) redbuf[w][16 * mt + 4 * q + rr] = v;
        }
    }
    __syncthreads();

    if (tid < 128) {
        int p = p0 + tid;
        float lsum = 0.f;
        if (p < P_PAIRS) {
            // recompute j for label
            float disc = 1046529.f - 8.f * (float)p;
            int i = (int)((1023.f - sqrtf(disc)) * 0.5f);
            if (i < 0) i = 0;
            if (i > NN - 1) i = NN - 1;
            while (i > 0 && i * (1023 - i) / 2 > p) i--;
            while ((i + 1) * (1022 - i) / 2 <= p) i++;
            int j = i + 1 + (p - i * (1023 - i) / 2);

            float logit = redbuf[0][tid] + redbuf[1][tid] +
                          redbuf[2][tid] + redbuf[3][tid] + b3[0];
            float label = (j < MM) ? 1.f : 0.f;
            lsum = fmaxf(logit, 0.f) - logit * label + log1pf(expf(-fabsf(logit)));
        }
        #pragma unroll
        for (int off = 32; off > 0; off >>= 1) lsum += __shfl_down(lsum, off);
        if ((tid & 63) == 0) red2[tid >> 6] = lsum;
    }
    __syncthreads();
    if (tid == 0) bcepart[bx] = red2[0] + red2[1];   // plain store, no atomic/fence
}

// ---------------- K3: final combine ----------------
__global__ __launch_bounds__(256) void k_final(const float* __restrict__ esp,
                                               const float* __restrict__ slp,
                                               const float* __restrict__ bcepart,
                                               float* __restrict__ out) {
    __shared__ float red[256];
    int t = threadIdx.x;

    float s = 0.f;
    for (int p = t; p < NPBLK_P; p += 256) s += bcepart[p];
    red[t] = s;
    __syncthreads();
    for (int st = 128; st > 0; st >>= 1) {
        if (t < st) red[t] += red[t + st];
        __syncthreads();
    }
    float bce_total = red[0];
    __syncthreads();

    float v = 0.f;
    if (t < NN) {
        float es = 0.f, sl = 0.f;
        #pragma unroll
        for (int s8 = 0; s8 < 8; s8++) {
            es += esp[s8 * NN + t];
            sl += slp[s8 * NN + t];
        }
        v = (float)(NN - 1 - t) * logf(es) - sl;
    }
    red[t] = v;
    __syncthreads();
    for (int st = 128; st > 0; st >>= 1) {
        if (t < st) red[t] += red[t + st];
        __syncthreads();
    }
    if (t == 0) {
        float closs = (-2.0f * (float)(NN - 1) / (float)NN) * red[0];
        out[0] = closs + bce_total / (float)P_PAIRS;
    }
}

extern "C" void kernel_launch(void* const* d_in, const int* in_sizes, int n_in,
                              void* d_out, int out_size, void* d_ws, size_t ws_size,
                              hipStream_t stream) {
    const float* emb = (const float*)d_in[0];
    const float* W1  = (const float*)d_in[1];
    const float* b1  = (const float*)d_in[2];
    const float* W2  = (const float*)d_in[3];
    const float* b2  = (const float*)d_in[4];
    const float* W3  = (const float*)d_in[5];
    const float* b3  = (const float*)d_in[6];
    float* out = (float*)d_out;

    float* ws = (float*)d_ws;
    float* esp     = ws;                         // 8*128
    float* slp     = ws + 1024;                  // 8*128
    float* bcepart = ws + 2048;                  // 448
    _Float16* zH  = (_Float16*)(ws + 3072);      // 512*768 frag-tiled
    _Float16* W1H = zH + B * D;                  // 512*768 frag-tiled
    _Float16* W2H = W1H + 2 * H * D;             // 256*256 frag-tiled
    _Float16* Up  = W2H + H * H;                 // 512*256 row-major
    _Float16* Vv  = Up + B * H;                  // 512*256 row-major

    k_prep<<<160, 256, 0, stream>>>(emb, W1, W2, zH, W1H, W2H);
    k_uv<<<256, 128, 0, stream>>>(zH, W1H, b1, Up, Vv);
    k_pairs<<<NPBLK_P + 16, 256, 0, stream>>>(Up, Vv, W2H, zH, b2, W3, b3,
                                              bcepart, esp, slp);
    k_final<<<1, 256, 0, stream>>>(esp, slp, bcepart, out);
}